// Round 7
// baseline (268.831 us; speedup 1.0000x reference)
//
#include <hip/hip_runtime.h>
#include <math.h>

#define HEADS 12
#define HSZ   64
#define SEQ   512
#define HID   768
#define NOUT  1536      // HEADS*2*HSZ
#define NEGQ  1.25e11f  // 1e12 / 8

typedef _Float16 f16x8 __attribute__((ext_vector_type(8)));
typedef _Float16 f16x4 __attribute__((ext_vector_type(4)));
typedef float    f32x4 __attribute__((ext_vector_type(4)));
typedef int      i32x4 __attribute__((ext_vector_type(4)));
typedef int      i32x8 __attribute__((ext_vector_type(8)));

__device__ __forceinline__ void async_ld16(const void* g, void* l) {
  __builtin_amdgcn_global_load_lds(
      (__attribute__((address_space(1))) void*)g,
      (__attribute__((address_space(3))) void*)l, 16, 0, 0);
}

// ---------------------------------------------------------------------------
// prep: hidden fp32 -> fp8 e4m3 (k-major) ; W fp32 (KxN) -> Wt8 fp8 (NxK) ;
// sincos table. (verified round-1 code, unchanged)
// ---------------------------------------------------------------------------
__global__ __launch_bounds__(256) void prep_k(
    const float* __restrict__ hidden, const float* __restrict__ W,
    unsigned char* __restrict__ Xb8, unsigned char* __restrict__ Wt8,
    float2* __restrict__ tab)
{
  __shared__ float t_lds[32][33];
  const int b = blockIdx.x;
  const int t = threadIdx.x;
  if (b < 1152) {                     // W transpose+cvt: 24 (K/32) x 48 (N/32)
    const int tk = b % 24, tn = b / 24;
    const int k0 = tk * 32, n0 = tn * 32;
    const int tx = t & 31, ty = t >> 5;
#pragma unroll
    for (int r = 0; r < 4; ++r)
      t_lds[ty + r * 8][tx] = W[(size_t)(k0 + ty + r * 8) * NOUT + n0 + tx];
    __syncthreads();
    const int nl = t >> 3, kg = t & 7;     // each thread packs 4 k into 1 int
    int w = __builtin_amdgcn_cvt_pk_fp8_f32(t_lds[kg * 4 + 0][nl],
                                            t_lds[kg * 4 + 1][nl], 0, false);
    w = __builtin_amdgcn_cvt_pk_fp8_f32(t_lds[kg * 4 + 2][nl],
                                        t_lds[kg * 4 + 3][nl], w, true);
    *(int*)&Wt8[(size_t)(n0 + nl) * HID + k0 + kg * 4] = w;
  } else if (b < 1152 + 1536) {       // hidden cvt: coalesced float4 reads
    const int base = (b - 1152) * 1024;
    const float4* src4 = (const float4*)hidden;
    int* dst = (int*)Xb8;
#pragma unroll
    for (int p = 0; p < 4; ++p) {
      const int i = base + p * 256 + t;
      const float4 v = src4[i];
      int o = __builtin_amdgcn_cvt_pk_fp8_f32(v.x, v.y, 0, false);
      o = __builtin_amdgcn_cvt_pk_fp8_f32(v.z, v.w, o, true);
      dst[i] = o;
    }
  } else {                            // sincos table: 512 pos x 32 freqs
    const int e = (b - 2688) * 256 + t;   // < 16384
    const int si = e >> 5, fi = e & 31;
    float inv = powf(10000.f, -(float)fi / 32.f);
    float ang = (float)si * inv;
    float sv, cv;
    sincosf(ang, &sv, &cv);
    tab[e] = make_float2(cv, sv);
  }
}

// ---------------------------------------------------------------------------
// GEMM1 + masked-tile fill + FUSED DIAGONAL S-tiles, one dispatch:
//   blocks   0..767  : 128x128 GEMM1 tile (m-tile mi=blk&63, head=blk>>6):
//                      MX-fp8 MFMA -> bias+RoPE -> q/k to LDS -> qb/kb stores
//                      -> then compute the DIAGONAL S-tile (bb=mi>>2,
//                      mt=nt=mi&3) straight from the LDS q/k (the block owns
//                      exactly those 128 rows), mask, sbuf-bounce, store.
//                      Moves 50 MB of output into gemm1's compute shadow and
//                      kills those tiles' q/k re-reads.
//   blocks 768..1919 : pure-store masked tiles (mt>nt, am-only dependency).
// ---------------------------------------------------------------------------
__global__ __launch_bounds__(256) void gemm1_k(
    const unsigned char* __restrict__ Xb8, const unsigned char* __restrict__ Wt8,
    const float* __restrict__ bias, const float2* __restrict__ tab,
    const int* __restrict__ am, float* __restrict__ out,
    _Float16* __restrict__ qb, _Float16* __restrict__ kb)
{
  __shared__ __align__(16) int shm[8192];   // 32 KB: As4|Bs4, later sbuf
  int* As4 = shm;                           // 128 rows x 128 fp8 (16 KB)
  int* Bs4 = shm + 4096;
  const int tid = threadIdx.x;
  const int blk = blockIdx.x;

  if (blk >= 768) {                   // masked-tile fill (am-only dependency)
    const int idx = blk - 768;        // 0..1151
    const int bh = idx / 6, f = idx % 6;
    const int te = (0xEDC984 >> (f * 4)) & 15;   // (1,0)(2,0)(2,1)(3,0)(3,1)(3,2)
    const int m0 = (te >> 2) * 128, n0 = (te & 3) * 128;
    const int* amb = am + (bh / HEADS) * SEQ;
    float* obase = out + (size_t)bh * SEQ * SEQ;
#pragma unroll
    for (int p = 0; p < 16; ++p) {
      const int ff = p * 256 + tid;
      const int row = ff >> 5, c4 = (ff & 31) * 4;
      const int m = m0 + row;
      const float amm = (float)amb[m];
      const int nb = n0 + c4;
      const int4 a4 = *(const int4*)&amb[nb];
      f32x4 v;
      v[0] = -(2.f - amm * (float)a4.x) * NEGQ;
      v[1] = -(2.f - amm * (float)a4.y) * NEGQ;
      v[2] = -(2.f - amm * (float)a4.z) * NEGQ;
      v[3] = -(2.f - amm * (float)a4.w) * NEGQ;
      __builtin_nontemporal_store(v, (f32x4*)&obase[(size_t)m * SEQ + nb]);
    }
    return;
  }

  const int lane = tid & 63;
  const int mi = blk & 63;
  const int m0 = mi * 128;
  const int h = blk >> 6;             // head 0..11
  const int n0 = h * 128;
  const int wm = ((tid >> 6) & 1) * 64;
  const int wn = (tid >> 7) * 64;
  const int lrow = lane & 15;
  const int q = lane >> 4;

  f32x4 acc[4][4] = {};

  // prologue: stage tile kt=0
#pragma unroll
  for (int c = 0; c < 4; ++c) {
    const int s = tid + c * 256;
    const int row = s >> 3, cc = s & 7;
    const int so = (((cc >> 1) ^ (row & 3)) << 5) + ((cc & 1) << 4);
    async_ld16(Xb8 + (size_t)(m0 + row) * HID + so, (char*)As4 + s * 16);
    async_ld16(Wt8 + (size_t)(n0 + row) * HID + so, (char*)Bs4 + s * 16);
  }

  for (int kt = 0; kt < 6; ++kt) {
    __syncthreads();                  // staged tile kt ready (vmcnt drained)
    i32x8 af[4], bf[4];
#pragma unroll
    for (int i = 0; i < 4; ++i) {
      const int ra = wm + i * 16 + lrow;
      const int oa = ra * 32 + ((q ^ (ra & 3)) << 3);
      i32x4 lo = *(const i32x4*)&As4[oa];
      i32x4 hi = *(const i32x4*)&As4[oa + 4];
      af[i] = (i32x8){lo.x, lo.y, lo.z, lo.w, hi.x, hi.y, hi.z, hi.w};
      const int rb = wn + i * 16 + lrow;
      const int ob = rb * 32 + ((q ^ (rb & 3)) << 3);
      lo = *(const i32x4*)&Bs4[ob];
      hi = *(const i32x4*)&Bs4[ob + 4];
      bf[i] = (i32x8){lo.x, lo.y, lo.z, lo.w, hi.x, hi.y, hi.z, hi.w};
    }
    __syncthreads();                  // all waves done reading LDS tile kt
    if (kt < 5) {                     // stage kt+1 under the MFMAs
      const int kbase = (kt + 1) * 128;
#pragma unroll
      for (int c = 0; c < 4; ++c) {
        const int s = tid + c * 256;
        const int row = s >> 3, cc = s & 7;
        const int so = (((cc >> 1) ^ (row & 3)) << 5) + ((cc & 1) << 4);
        async_ld16(Xb8 + (size_t)(m0 + row) * HID + kbase + so, (char*)As4 + s * 16);
        async_ld16(Wt8 + (size_t)(n0 + row) * HID + kbase + so, (char*)Bs4 + s * 16);
      }
    }
#pragma unroll
    for (int i = 0; i < 4; ++i)
#pragma unroll
      for (int j = 0; j < 4; ++j)
        acc[i][j] = __builtin_amdgcn_mfma_scale_f32_16x16x128_f8f6f4(
            bf[j], af[i], acc[i][j], 0, 0,
            0, 0x7F7F7F7F, 0, 0x7F7F7F7F);   // E8M0 0x7F = 1.0 in every byte
  }
  __syncthreads();                    // frags-in-regs; LDS now free for epilogue

  // epilogue phase 1: bias + interleaved RoPE -> swizzled LDS q/k tiles.
  {
    const int qlane = lane >> 4;
    const int rbase = wm + (lane & 15);
    f16x4* sdst = wn ? (f16x4*)Bs4 : (f16x4*)As4;
#pragma unroll
    for (int j = 0; j < 4; ++j) {
      const int d0 = j * 16 + qlane * 4;        // 0..60, multiple of 4
      const int nb = n0 + wn + d0;
      const float4 b4 = *(const float4*)&bias[nb];
      const int fi0 = d0 >> 1;                  // even
#pragma unroll
      for (int i = 0; i < 4; ++i) {
        const int r = rbase + i * 16;           // row within block tile
        const int m = m0 + r;
        const int si = m & (SEQ - 1);
        const float4 cs = *(const float4*)&tab[si * 32 + fi0];  // c0,s0,c1,s1
        const float v0 = acc[i][j][0] + b4.x;
        const float v1 = acc[i][j][1] + b4.y;
        const float v2 = acc[i][j][2] + b4.z;
        const float v3 = acc[i][j][3] + b4.w;
        f16x4 o;
        o.x = (_Float16)fmaf(v0, cs.x, -v1 * cs.y);
        o.y = (_Float16)fmaf(v1, cs.x, v0 * cs.y);
        o.z = (_Float16)fmaf(v2, cs.z, -v3 * cs.w);
        o.w = (_Float16)fmaf(v3, cs.z, v2 * cs.w);
        // 8B-unit XOR swizzle; read side stays 16B-pair aligned
        sdst[r * 16 + ((d0 >> 2) ^ ((r & 7) << 1))] = o;
      }
    }
  }
  __syncthreads();

  // epilogue phase 2: contiguous f16x8 qb/kb stores (wave writes 1 KB runs).
  {
    const int bb = m0 >> 9;
    const int si0 = m0 & (SEQ - 1);
    _Float16* qdst = qb + ((size_t)(bb * HEADS + h) * SEQ + si0) * HSZ;
    _Float16* kdst = kb + ((size_t)(bb * HEADS + h) * SEQ + si0) * HSZ;
#pragma unroll
    for (int p = 0; p < 4; ++p) {
      const int idx = p * 256 + tid;
      const int row = idx >> 3, v = idx & 7;    // 8 x 16B per 128B row
      const int sv = v ^ (row & 7);             // inverse of write swizzle
      f16x8 qv = ((const f16x8*)As4)[row * 8 + sv];
      f16x8 kv = ((const f16x8*)Bs4)[row * 8 + sv];
      *(f16x8*)(qdst + row * HSZ + v * 8) = qv;
      *(f16x8*)(kdst + row * HSZ + v * 8) = kv;
    }
  }

  // ======== fused DIAGONAL S-tile: bb = mi>>2, mt = nt = mi&3 ========
  // q/k frags read from LDS (mega_k-verified f16x8 swizzled read), then the
  // verified gemm2 MFMA + mask + sbuf-bounce epilogue with m0d = n0d.
  const int bb2 = mi >> 2;
  const int m0d = (mi & 3) * 128;             // seq-space tile origin
  const int* amb = am + bb2 * SEQ;
  float* obase = out + (size_t)(bb2 * HEADS + h) * SEQ * SEQ;

  f16x8 af2[4][2], bf2[4][2];
  {
    const f16x8* q16 = (const f16x8*)As4;
    const f16x8* k16 = (const f16x8*)Bs4;
#pragma unroll
    for (int i = 0; i < 4; ++i)
#pragma unroll
      for (int hh = 0; hh < 2; ++hh) {
        const int rA = wm + i * 16 + lrow;    // row within tile 0..127
        af2[i][hh] = q16[rA * 8 + ((hh * 4 + q) ^ (rA & 7))];
        const int rB = wn + i * 16 + lrow;
        bf2[i][hh] = k16[rB * 8 + ((hh * 4 + q) ^ (rB & 7))];
      }
  }

  f32x4 acc2[4][4] = {};
#pragma unroll
  for (int hh = 0; hh < 2; ++hh)
#pragma unroll
    for (int i = 0; i < 4; ++i)
#pragma unroll
      for (int j = 0; j < 4; ++j)
        acc2[i][j] = __builtin_amdgcn_mfma_f32_16x16x32_f16(
            bf2[j][hh], af2[i][hh], acc2[i][j], 0, 0, 0);

  __syncthreads();                    // q/k LDS reads done; shm -> sbuf
  float* sbuf = (float*)shm;          // 64 x 128 f32 (32 KB)
  const int qlane = lane >> 4;
  const int rloc = lane & 15;
  const int wmp = wm >> 6;            // 0 or 1: which phase this wave writes
  for (int ph = 0; ph < 2; ++ph) {
    if (wmp == ph) {
#pragma unroll
      for (int i = 0; i < 4; ++i) {
        const int r = i * 16 + rloc;            // 0..63 within phase
        const int m = m0d + wm + r;             // seq row
        const float amm = (float)amb[m];
#pragma unroll
        for (int j = 0; j < 4; ++j) {
          const int nb = m0d + wn + j * 16 + qlane * 4;
          const int4 a4 = *(const int4*)&amb[nb];
          f32x4 v;
          v[0] = fmaf(acc2[i][j][0], 0.125f,
                      -((float)(nb + 0 < m) + (1.f - amm * (float)a4.x)) * NEGQ);
          v[1] = fmaf(acc2[i][j][1], 0.125f,
                      -((float)(nb + 1 < m) + (1.f - amm * (float)a4.y)) * NEGQ);
          v[2] = fmaf(acc2[i][j][2], 0.125f,
                      -((float)(nb + 2 < m) + (1.f - amm * (float)a4.z)) * NEGQ);
          v[3] = fmaf(acc2[i][j][3], 0.125f,
                      -((float)(nb + 3 < m) + (1.f - amm * (float)a4.w)) * NEGQ);
          // 16B-unit t (0..31), XOR-swizzle with (r&7): 8-way (optimal b128)
          const int t = ((wn >> 2) + j * 4 + qlane) ^ (r & 7);
          *(f32x4*)&sbuf[r * 128 + t * 4] = v;
        }
      }
    }
    __syncthreads();
    const int rowbase = m0d + ph * 64;
#pragma unroll
    for (int p = 0; p < 8; ++p) {
      const int idx = p * 256 + tid;
      const int row = idx >> 5, t = idx & 31;   // 32 x 16B per 512B row
      f32x4 v = *(const f32x4*)&sbuf[row * 128 + ((t ^ (row & 7)) * 4)];
      __builtin_nontemporal_store(
          v, (f32x4*)&obase[(size_t)(rowbase + row) * SEQ + m0d + t * 4]);
    }
    __syncthreads();
  }
}

// ---------------------------------------------------------------------------
// GEMM2: per (b,h): only the 6 strictly-upper tiles (mt < nt); diagonal tiles
// were fused into gemm1, masked tiles into the fill blocks. XCD-grouped
// mapping keeps each (b,h)'s 128 KB q/k slab L2-local. Epilogue bounces
// masked acc through a 32 KB swizzled LDS tile -> 512 B contiguous stores.
// ---------------------------------------------------------------------------
__global__ __launch_bounds__(256) void gemm2_k(
    const _Float16* __restrict__ qb, const _Float16* __restrict__ kb,
    const int* __restrict__ am, float* __restrict__ out)
{
  __shared__ __align__(16) float sbuf[64 * 128];   // 32 KB
  const int tid = threadIdx.x;
  const int blk = blockIdx.x;                 // 0..1151
  const int xcd = blk & 7;
  const int slot = blk >> 3;                  // 0..143: 24 bh x 6 tiles
  const int bh = xcd * 24 + slot / 6;
  const int bb = bh / HEADS;
  const int te = (0xB76321 >> ((slot % 6) * 4)) & 15;  // (0,1)(0,2)(0,3)(1,2)(1,3)(2,3)
  const int mt = te >> 2, nt = te & 3;        // mt < nt guaranteed
  const int m0 = mt * 128, n0 = nt * 128;
  const int* amb = am + bb * SEQ;
  float* obase = out + (size_t)bh * SEQ * SEQ;

  const _Float16* qg = qb + (size_t)bh * SEQ * HSZ;
  const _Float16* kg = kb + (size_t)bh * SEQ * HSZ;
  const int lane = tid & 63;
  const int wm = ((tid >> 6) & 1) * 64;
  const int wn = (tid >> 7) * 64;
  const int lrow = lane & 15;
  const int lk = (lane >> 4) * 8;

  f16x8 af[4][2], bf[4][2];
#pragma unroll
  for (int i = 0; i < 4; ++i)
#pragma unroll
    for (int h = 0; h < 2; ++h) {
      af[i][h] = *(const f16x8*)(qg + (size_t)(m0 + wm + i * 16 + lrow) * HSZ + h * 32 + lk);
      bf[i][h] = *(const f16x8*)(kg + (size_t)(n0 + wn + i * 16 + lrow) * HSZ + h * 32 + lk);
    }

  f32x4 acc[4][4] = {};
#pragma unroll
  for (int h = 0; h < 2; ++h)
#pragma unroll
    for (int i = 0; i < 4; ++i)
#pragma unroll
      for (int j = 0; j < 4; ++j)
        acc[i][j] = __builtin_amdgcn_mfma_f32_16x16x32_f16(bf[j][h], af[i][h], acc[i][j], 0, 0, 0);

  // epilogue: two 64-row phases through swizzled LDS, then contiguous stores
  const int qlane = lane >> 4;
  const int rloc = lane & 15;
  const int wmp = wm >> 6;          // 0 or 1: which phase this wave writes
  for (int ph = 0; ph < 2; ++ph) {
    if (wmp == ph) {
#pragma unroll
      for (int i = 0; i < 4; ++i) {
        const int r = i * 16 + rloc;            // 0..63 within phase
        const int m = m0 + wm + r;              // global row
        const float amm = (float)amb[m];
#pragma unroll
        for (int j = 0; j < 4; ++j) {
          const int nb = n0 + wn + j * 16 + qlane * 4;
          const int4 a4 = *(const int4*)&amb[nb];
          f32x4 v;
          v[0] = fmaf(acc[i][j][0], 0.125f,
                      -((float)(nb + 0 < m) + (1.f - amm * (float)a4.x)) * NEGQ);
          v[1] = fmaf(acc[i][j][1], 0.125f,
                      -((float)(nb + 1 < m) + (1.f - amm * (float)a4.y)) * NEGQ);
          v[2] = fmaf(acc[i][j][2], 0.125f,
                      -((float)(nb + 2 < m) + (1.f - amm * (float)a4.z)) * NEGQ);
          v[3] = fmaf(acc[i][j][3], 0.125f,
                      -((float)(nb + 3 < m) + (1.f - amm * (float)a4.w)) * NEGQ);
          // 16B-unit t (0..31), XOR-swizzle with (r&7): 8-way (optimal b128)
          const int t = ((wn >> 2) + j * 4 + qlane) ^ (r & 7);
          *(f32x4*)&sbuf[r * 128 + t * 4] = v;
        }
      }
    }
    __syncthreads();
    const int rowbase = m0 + ph * 64;
#pragma unroll
    for (int p = 0; p < 8; ++p) {
      const int idx = p * 256 + tid;
      const int row = idx >> 5, t = idx & 31;   // 32 x 16B per 512B row
      f32x4 v = *(const f32x4*)&sbuf[row * 128 + ((t ^ (row & 7)) * 4)];
      __builtin_nontemporal_store(
          v, (f32x4*)&obase[(size_t)(rowbase + row) * SEQ + n0 + t * 4]);
    }
    __syncthreads();
  }
}

// ---------------------------------------------------------------------------
extern "C" void kernel_launch(void* const* d_in, const int* in_sizes, int n_in,
                              void* d_out, int out_size, void* d_ws, size_t ws_size,
                              hipStream_t stream) {
  const float* hidden = (const float*)d_in[0];
  const int*   am     = (const int*)d_in[1];
  const float* W      = (const float*)d_in[2];
  const float* bias   = (const float*)d_in[3];
  float* out = (float*)d_out;
  char* ws = (char*)d_ws;
  // workspace layout (16B-aligned), total ~32.8 MB
  unsigned char* Xb8 = (unsigned char*)(ws);              // 8192*768  = 6,291,456
  unsigned char* Wt8 = (unsigned char*)(ws + 6291456);    // 1536*768  = 1,179,648
  _Float16* qb = (_Float16*)(ws + 7471104);               // 12,582,912
  _Float16* kb = (_Float16*)(ws + 20054016);              // 12,582,912
  float2*   tab = (float2*)(ws + 32636928);               // 131,072

  prep_k<<<dim3(2752), dim3(256), 0, stream>>>(hidden, W, Xb8, Wt8, tab);
  gemm1_k<<<dim3(1920), dim3(256), 0, stream>>>(Xb8, Wt8, bias, tab, am, out, qb, kb);
  gemm2_k<<<dim3(1152), dim3(256), 0, stream>>>(qb, kb, am, out);
}

// Round 8
// 255.577 us; speedup vs baseline: 1.0519x; 1.0519x over previous
//
#include <hip/hip_runtime.h>
#include <math.h>

#define HEADS 12
#define HSZ   64
#define SEQ   512
#define HID   768
#define NOUT  1536      // HEADS*2*HSZ
#define NEGQ  1.25e11f  // 1e12 / 8

typedef _Float16 f16x8 __attribute__((ext_vector_type(8)));
typedef _Float16 f16x4 __attribute__((ext_vector_type(4)));
typedef float    f32x4 __attribute__((ext_vector_type(4)));
typedef int      i32x4 __attribute__((ext_vector_type(4)));
typedef int      i32x8 __attribute__((ext_vector_type(8)));

__device__ __forceinline__ void async_ld16(const void* g, void* l) {
  __builtin_amdgcn_global_load_lds(
      (__attribute__((address_space(1))) void*)g,
      (__attribute__((address_space(3))) void*)l, 16, 0, 0);
}

// ---------------------------------------------------------------------------
// prep: hidden fp32 -> fp8 e4m3 (k-major) ; W fp32 (KxN) -> Wt8 fp8 (NxK) ;
// sincos table. (verified round-1 code, unchanged)
// ---------------------------------------------------------------------------
__global__ __launch_bounds__(256) void prep_k(
    const float* __restrict__ hidden, const float* __restrict__ W,
    unsigned char* __restrict__ Xb8, unsigned char* __restrict__ Wt8,
    float2* __restrict__ tab)
{
  __shared__ float t_lds[32][33];
  const int b = blockIdx.x;
  const int t = threadIdx.x;
  if (b < 1152) {                     // W transpose+cvt: 24 (K/32) x 48 (N/32)
    const int tk = b % 24, tn = b / 24;
    const int k0 = tk * 32, n0 = tn * 32;
    const int tx = t & 31, ty = t >> 5;
#pragma unroll
    for (int r = 0; r < 4; ++r)
      t_lds[ty + r * 8][tx] = W[(size_t)(k0 + ty + r * 8) * NOUT + n0 + tx];
    __syncthreads();
    const int nl = t >> 3, kg = t & 7;     // each thread packs 4 k into 1 int
    int w = __builtin_amdgcn_cvt_pk_fp8_f32(t_lds[kg * 4 + 0][nl],
                                            t_lds[kg * 4 + 1][nl], 0, false);
    w = __builtin_amdgcn_cvt_pk_fp8_f32(t_lds[kg * 4 + 2][nl],
                                        t_lds[kg * 4 + 3][nl], w, true);
    *(int*)&Wt8[(size_t)(n0 + nl) * HID + k0 + kg * 4] = w;
  } else if (b < 1152 + 1536) {       // hidden cvt: coalesced float4 reads
    const int base = (b - 1152) * 1024;
    const float4* src4 = (const float4*)hidden;
    int* dst = (int*)Xb8;
#pragma unroll
    for (int p = 0; p < 4; ++p) {
      const int i = base + p * 256 + t;
      const float4 v = src4[i];
      int o = __builtin_amdgcn_cvt_pk_fp8_f32(v.x, v.y, 0, false);
      o = __builtin_amdgcn_cvt_pk_fp8_f32(v.z, v.w, o, true);
      dst[i] = o;
    }
  } else {                            // sincos table: 512 pos x 32 freqs
    const int e = (b - 2688) * 256 + t;   // < 16384
    const int si = e >> 5, fi = e & 31;
    float inv = powf(10000.f, -(float)fi / 32.f);
    float ang = (float)si * inv;
    float sv, cv;
    sincosf(ang, &sv, &cv);
    tab[e] = make_float2(cv, sv);
  }
}

// ---------------------------------------------------------------------------
// GEMM1 + masked-tile fill, one dispatch:
//   blocks   0..767  : 128x128 GEMM tiles (m = blk&63, head = blk>>6),
//                      MX-fp8 MFMA, staged-ahead LDS (verified round-5 code)
//   blocks 768..1919 : pure-store blocks writing the 6 tril-masked 128x128
//                      tiles per (b,h) — they depend only on attention_mask,
//                      so their 75 MB write stream overlaps gemm1's compute
//                      (gemm1 is compute-bound, HBM idle).
// ---------------------------------------------------------------------------
__global__ __launch_bounds__(256) void gemm1_k(
    const unsigned char* __restrict__ Xb8, const unsigned char* __restrict__ Wt8,
    const float* __restrict__ bias, const float2* __restrict__ tab,
    const int* __restrict__ am, float* __restrict__ out,
    _Float16* __restrict__ qb, _Float16* __restrict__ kb)
{
  __shared__ __align__(16) int As4[4096];   // 128 rows x 128 fp8 (16 KB)
  __shared__ __align__(16) int Bs4[4096];
  const int tid = threadIdx.x;
  const int blk = blockIdx.x;

  if (blk >= 768) {                   // masked-tile fill (am-only dependency)
    const int idx = blk - 768;        // 0..1151
    const int bh = idx / 6, f = idx % 6;
    const int te = (0xEDC984 >> (f * 4)) & 15;   // (1,0)(2,0)(2,1)(3,0)(3,1)(3,2)
    const int m0 = (te >> 2) * 128, n0 = (te & 3) * 128;
    const int* amb = am + (bh / HEADS) * SEQ;
    float* obase = out + (size_t)bh * SEQ * SEQ;
#pragma unroll
    for (int p = 0; p < 16; ++p) {
      const int ff = p * 256 + tid;
      const int row = ff >> 5, c4 = (ff & 31) * 4;
      const int m = m0 + row;
      const float amm = (float)amb[m];
      const int nb = n0 + c4;
      const int4 a4 = *(const int4*)&amb[nb];
      f32x4 v;
      v[0] = -(2.f - amm * (float)a4.x) * NEGQ;
      v[1] = -(2.f - amm * (float)a4.y) * NEGQ;
      v[2] = -(2.f - amm * (float)a4.z) * NEGQ;
      v[3] = -(2.f - amm * (float)a4.w) * NEGQ;
      __builtin_nontemporal_store(v, (f32x4*)&obase[(size_t)m * SEQ + nb]);
    }
    return;
  }

  const int lane = tid & 63;
  const int m0 = (blk & 63) * 128;
  const int h = blk >> 6;             // head 0..11
  const int n0 = h * 128;
  const int wm = ((tid >> 6) & 1) * 64;
  const int wn = (tid >> 7) * 64;
  const int lrow = lane & 15;
  const int q = lane >> 4;

  f32x4 acc[4][4] = {};

  // prologue: stage tile kt=0
#pragma unroll
  for (int c = 0; c < 4; ++c) {
    const int s = tid + c * 256;
    const int row = s >> 3, cc = s & 7;
    const int so = (((cc >> 1) ^ (row & 3)) << 5) + ((cc & 1) << 4);
    async_ld16(Xb8 + (size_t)(m0 + row) * HID + so, (char*)As4 + s * 16);
    async_ld16(Wt8 + (size_t)(n0 + row) * HID + so, (char*)Bs4 + s * 16);
  }

  for (int kt = 0; kt < 6; ++kt) {
    __syncthreads();                  // staged tile kt ready (vmcnt drained)
    i32x8 af[4], bf[4];
#pragma unroll
    for (int i = 0; i < 4; ++i) {
      const int ra = wm + i * 16 + lrow;
      const int oa = ra * 32 + ((q ^ (ra & 3)) << 3);
      i32x4 lo = *(const i32x4*)&As4[oa];
      i32x4 hi = *(const i32x4*)&As4[oa + 4];
      af[i] = (i32x8){lo.x, lo.y, lo.z, lo.w, hi.x, hi.y, hi.z, hi.w};
      const int rb = wn + i * 16 + lrow;
      const int ob = rb * 32 + ((q ^ (rb & 3)) << 3);
      lo = *(const i32x4*)&Bs4[ob];
      hi = *(const i32x4*)&Bs4[ob + 4];
      bf[i] = (i32x8){lo.x, lo.y, lo.z, lo.w, hi.x, hi.y, hi.z, hi.w};
    }
    __syncthreads();                  // all waves done reading LDS tile kt
    if (kt < 5) {                     // stage kt+1 under the MFMAs
      const int kbase = (kt + 1) * 128;
#pragma unroll
      for (int c = 0; c < 4; ++c) {
        const int s = tid + c * 256;
        const int row = s >> 3, cc = s & 7;
        const int so = (((cc >> 1) ^ (row & 3)) << 5) + ((cc & 1) << 4);
        async_ld16(Xb8 + (size_t)(m0 + row) * HID + kbase + so, (char*)As4 + s * 16);
        async_ld16(Wt8 + (size_t)(n0 + row) * HID + kbase + so, (char*)Bs4 + s * 16);
      }
    }
#pragma unroll
    for (int i = 0; i < 4; ++i)
#pragma unroll
      for (int j = 0; j < 4; ++j)
        acc[i][j] = __builtin_amdgcn_mfma_scale_f32_16x16x128_f8f6f4(
            bf[j], af[i], acc[i][j], 0, 0,
            0, 0x7F7F7F7F, 0, 0x7F7F7F7F);   // E8M0 0x7F = 1.0 in every byte
  }
  __syncthreads();                    // frags-in-regs; LDS now free for epilogue

  // epilogue phase 1: bias + interleaved RoPE -> swizzled LDS q/k tiles.
  {
    const int qlane = lane >> 4;
    const int rbase = wm + (lane & 15);
    f16x4* sdst = wn ? (f16x4*)Bs4 : (f16x4*)As4;
#pragma unroll
    for (int j = 0; j < 4; ++j) {
      const int d0 = j * 16 + qlane * 4;        // 0..60, multiple of 4
      const int nb = n0 + wn + d0;
      const float4 b4 = *(const float4*)&bias[nb];
      const int fi0 = d0 >> 1;                  // even
#pragma unroll
      for (int i = 0; i < 4; ++i) {
        const int r = rbase + i * 16;           // row within block tile
        const int m = m0 + r;
        const int si = m & (SEQ - 1);
        const float4 cs = *(const float4*)&tab[si * 32 + fi0];  // c0,s0,c1,s1
        const float v0 = acc[i][j][0] + b4.x;
        const float v1 = acc[i][j][1] + b4.y;
        const float v2 = acc[i][j][2] + b4.z;
        const float v3 = acc[i][j][3] + b4.w;
        f16x4 o;
        o.x = (_Float16)fmaf(v0, cs.x, -v1 * cs.y);
        o.y = (_Float16)fmaf(v1, cs.x, v0 * cs.y);
        o.z = (_Float16)fmaf(v2, cs.z, -v3 * cs.w);
        o.w = (_Float16)fmaf(v3, cs.z, v2 * cs.w);
        // 8B-unit XOR swizzle; read side stays 16B-pair aligned
        sdst[r * 16 + ((d0 >> 2) ^ ((r & 7) << 1))] = o;
      }
    }
  }
  __syncthreads();

  // epilogue phase 2: contiguous f16x8 stores (wave writes 1 KB runs).
  {
    const int bb = m0 >> 9;
    const int si0 = m0 & (SEQ - 1);
    _Float16* qdst = qb + ((size_t)(bb * HEADS + h) * SEQ + si0) * HSZ;
    _Float16* kdst = kb + ((size_t)(bb * HEADS + h) * SEQ + si0) * HSZ;
#pragma unroll
    for (int p = 0; p < 4; ++p) {
      const int idx = p * 256 + tid;
      const int row = idx >> 3, v = idx & 7;    // 8 x 16B per 128B row
      const int sv = v ^ (row & 7);             // inverse of write swizzle
      f16x8 qv = ((const f16x8*)As4)[row * 8 + sv];
      f16x8 kv = ((const f16x8*)Bs4)[row * 8 + sv];
      *(f16x8*)(qdst + row * HSZ + v * 8) = qv;
      *(f16x8*)(kdst + row * HSZ + v * 8) = kv;
    }
  }
}

// ---------------------------------------------------------------------------
// GEMM2: per (b,h): only the 10 unmasked tiles (nt >= mt); masked tiles were
// written during the gemm1 dispatch. XCD-grouped mapping keeps each (b,h)'s
// 128 KB q/k slab L2-local. Epilogue bounces masked acc through a 32 KB
// swizzled LDS tile in two 64-row phases -> 512 B contiguous nt stores.
// ---------------------------------------------------------------------------
__global__ __launch_bounds__(256) void gemm2_k(
    const _Float16* __restrict__ qb, const _Float16* __restrict__ kb,
    const int* __restrict__ am, float* __restrict__ out)
{
  __shared__ __align__(16) float sbuf[64 * 128];   // 32 KB
  const int tid = threadIdx.x;
  const int blk = blockIdx.x;                 // 0..1919
  const int xcd = blk & 7;
  const int slot = blk >> 3;                  // 0..239: 24 bh x 10 tiles
  const int bh = xcd * 24 + slot / 10;
  const int bb = bh / HEADS;
  const int te = (int)((0xFBA7653210ULL >> ((slot % 10) * 4)) & 15);
  const int mt = te >> 2, nt = te & 3;        // nt >= mt guaranteed
  const int m0 = mt * 128, n0 = nt * 128;
  const int* amb = am + bb * SEQ;
  float* obase = out + (size_t)bh * SEQ * SEQ;

  const _Float16* qg = qb + (size_t)bh * SEQ * HSZ;
  const _Float16* kg = kb + (size_t)bh * SEQ * HSZ;
  const int lane = tid & 63;
  const int wm = ((tid >> 6) & 1) * 64;
  const int wn = (tid >> 7) * 64;
  const int lrow = lane & 15;
  const int lk = (lane >> 4) * 8;

  f16x8 af[4][2], bf[4][2];
#pragma unroll
  for (int i = 0; i < 4; ++i)
#pragma unroll
    for (int h = 0; h < 2; ++h) {
      af[i][h] = *(const f16x8*)(qg + (size_t)(m0 + wm + i * 16 + lrow) * HSZ + h * 32 + lk);
      bf[i][h] = *(const f16x8*)(kg + (size_t)(n0 + wn + i * 16 + lrow) * HSZ + h * 32 + lk);
    }

  f32x4 acc[4][4] = {};
#pragma unroll
  for (int h = 0; h < 2; ++h)
#pragma unroll
    for (int i = 0; i < 4; ++i)
#pragma unroll
      for (int j = 0; j < 4; ++j)
        acc[i][j] = __builtin_amdgcn_mfma_f32_16x16x32_f16(bf[j][h], af[i][h], acc[i][j], 0, 0, 0);

  // epilogue: two 64-row phases through swizzled LDS, then contiguous stores
  const int qlane = lane >> 4;
  const int rloc = lane & 15;
  const int wmp = wm >> 6;          // 0 or 1: which phase this wave writes
  for (int ph = 0; ph < 2; ++ph) {
    if (wmp == ph) {
#pragma unroll
      for (int i = 0; i < 4; ++i) {
        const int r = i * 16 + rloc;            // 0..63 within phase
        const int m = m0 + wm + r;              // global row
        const float amm = (float)amb[m];
#pragma unroll
        for (int j = 0; j < 4; ++j) {
          const int nb = n0 + wn + j * 16 + qlane * 4;
          const int4 a4 = *(const int4*)&amb[nb];
          f32x4 v;
          v[0] = fmaf(acc[i][j][0], 0.125f,
                      -((float)(nb + 0 < m) + (1.f - amm * (float)a4.x)) * NEGQ);
          v[1] = fmaf(acc[i][j][1], 0.125f,
                      -((float)(nb + 1 < m) + (1.f - amm * (float)a4.y)) * NEGQ);
          v[2] = fmaf(acc[i][j][2], 0.125f,
                      -((float)(nb + 2 < m) + (1.f - amm * (float)a4.z)) * NEGQ);
          v[3] = fmaf(acc[i][j][3], 0.125f,
                      -((float)(nb + 3 < m) + (1.f - amm * (float)a4.w)) * NEGQ);
          // 16B-unit t (0..31), XOR-swizzle with (r&7): 8-way (optimal b128)
          const int t = ((wn >> 2) + j * 4 + qlane) ^ (r & 7);
          *(f32x4*)&sbuf[r * 128 + t * 4] = v;
        }
      }
    }
    __syncthreads();
    const int rowbase = m0 + ph * 64;
#pragma unroll
    for (int p = 0; p < 8; ++p) {
      const int idx = p * 256 + tid;
      const int row = idx >> 5, t = idx & 31;   // 32 x 16B per 512B row
      f32x4 v = *(const f32x4*)&sbuf[row * 128 + ((t ^ (row & 7)) * 4)];
      __builtin_nontemporal_store(
          v, (f32x4*)&obase[(size_t)(rowbase + row) * SEQ + n0 + t * 4]);
    }
    __syncthreads();
  }
}

// ---------------------------------------------------------------------------
extern "C" void kernel_launch(void* const* d_in, const int* in_sizes, int n_in,
                              void* d_out, int out_size, void* d_ws, size_t ws_size,
                              hipStream_t stream) {
  const float* hidden = (const float*)d_in[0];
  const int*   am     = (const int*)d_in[1];
  const float* W      = (const float*)d_in[2];
  const float* bias   = (const float*)d_in[3];
  float* out = (float*)d_out;
  char* ws = (char*)d_ws;
  // workspace layout (16B-aligned), total ~32.8 MB
  unsigned char* Xb8 = (unsigned char*)(ws);              // 8192*768  = 6,291,456
  unsigned char* Wt8 = (unsigned char*)(ws + 6291456);    // 1536*768  = 1,179,648
  _Float16* qb = (_Float16*)(ws + 7471104);               // 12,582,912
  _Float16* kb = (_Float16*)(ws + 20054016);              // 12,582,912
  float2*   tab = (float2*)(ws + 32636928);               // 131,072

  prep_k<<<dim3(2752), dim3(256), 0, stream>>>(hidden, W, Xb8, Wt8, tab);
  gemm1_k<<<dim3(1920), dim3(256), 0, stream>>>(Xb8, Wt8, bias, tab, am, out, qb, kb);
  gemm2_k<<<dim3(1920), dim3(256), 0, stream>>>(qb, kb, am, out);
}